// Round 17
// baseline (127.746 us; speedup 1.0000x reference)
//
#include <hip/hip_runtime.h>

// NonlocalWeightedAverage v20: v14 loop (verbatim; best: 79.4 us fused) +
// combine folded via FENCELESS device-scope atomics.
// v19 post-mortem: xls4 interleave regressed fused 79.4->88.1 (conflicts
// unchanged, scatter cost) -- LDS micro-tuning closed; v14 floor is latency.
// Fold mechanism (avoids v16's fence storm and v18's no-launch): partials
// are atomicAdd'ed into pair-shared ws (device-scope = L3-coherent, m20;
// float add commutative -> bitwise == old p0+p1); s_waitcnt vmcnt(0) orders
// them before the pair-flag atomicAdd; last arriver reads the sums back via
// atomicAdd(p, 0.0f) (coherent read), normalizes, writes out. No fence ever
// issued -> no L2 invalidation storm. ws+flags zeroed by convert (stream-
// ordered). No spinning -> no deadlock. Eliminates combine kernel + gap.

#define NPIX 4096
#define ROWB  (528 * 16)       // 8 kchunks * 66 xslots * 16 B = 8448 B
#define SCALE 10.0f
#define XCH   2048             // x floats per channel per block (32 rows * 64)

typedef __attribute__((ext_vector_type(8))) short bf16x8;
typedef __attribute__((ext_vector_type(4))) float f32x4;

#define MF(a, b, c) __builtin_amdgcn_mfma_f32_16x16x32_bf16(a, b, c, 0, 0, 0)

__device__ __forceinline__ float blo(unsigned u) { return __uint_as_float(u << 16); }
__device__ __forceinline__ float bhi(unsigned u) { return __uint_as_float(u & 0xffff0000u); }

// 6 MFMAs into acc[T][KT]: dx outer, ks inner (v4-proven order).
#define MG(T, DBASE, KT) do {                                                 \
    _Pragma("unroll")                                                         \
    for (int dx = 0; dx < 3; ++dx)                                            \
        _Pragma("unroll")                                                     \
        for (int ks = 0; ks < 2; ++ks)                                        \
            acc[T][KT] = MF(AF[((DBASE) + dx) * 2 + ks], B2[ks][dx], acc[T][KT]); \
} while (0)

// myv is LOCAL key row (0..31) within this block's half
#define RETIRE(S, myv) do {                                                   \
    _Pragma("unroll")                                                         \
    for (int kt = 0; kt < 4; ++kt) {                                          \
        const int kx = kt * 16 + nl;                                          \
        const float xv0 = xls[(myv) * 64 + kx];                               \
        const float xv1 = xls[XCH + (myv) * 64 + kx];                         \
        const float xv2 = xls[2 * XCH + (myv) * 64 + kx];                     \
        _Pragma("unroll")                                                     \
        for (int rg = 0; rg < 4; ++rg) {                                      \
            const float e = __expf(fmaf(acc[S][kt][rg], SCALE, negM[rg]));    \
            l_[rg] += e;                                                      \
            A0[rg] = fmaf(e, xv0, A0[rg]);                                    \
            A1[rg] = fmaf(e, xv1, A1[rg]);                                    \
            A2[rg] = fmaf(e, xv2, A2[rg]);                                    \
        }                                                                     \
        acc[S][kt] = (f32x4){0.f, 0.f, 0.f, 0.f};                             \
    }                                                                         \
} while (0)

// Step t: feature row g(t) = R0 - 1 + t, t = 0..33 (loop runs to 35, guards
// false at 34,35). Staging: issue 2 dwordx4 loads of row g(t+2) at step
// START (latency hides under the MFMAs); ds_write after retire; barrier.
#define STEP(RM, SN, SR, tt) do {                                             \
    const int t_ = (tt);                                                      \
    uint4 Rv0 = (uint4){0u, 0u, 0u, 0u}, Rv1 = (uint4){0u, 0u, 0u, 0u};       \
    if (t_ <= 31) {                                                           \
        const int g2 = R0 + 1 + t_;                                           \
        if (g2 < 64) {                                                        \
            Rv0 = fbb[kc0 * NPIX + g2 * 64 + x];                              \
            Rv1 = fbb[kc1 * NPIX + g2 * 64 + x];                              \
        }                                                                     \
    }                                                                         \
    if (t_ <= 33) {                                                           \
        const char* base = ring + (RM) * ROWB + bu;                           \
        _Pragma("unroll")                                                     \
        for (int kt = 0; kt < 4; ++kt) {                                      \
            bf16x8 B2[2][3];                                                  \
            _Pragma("unroll")                                                 \
            for (int ks = 0; ks < 2; ++ks) {                                  \
                const char* p = base + (ks * 264 + kt * 16) * 16;             \
                B2[ks][0] = *(const bf16x8*)(p);                              \
                B2[ks][1] = *(const bf16x8*)(p + 16);                         \
                B2[ks][2] = *(const bf16x8*)(p + 32);                         \
            }                                                                 \
            if (t_ >= 2)              MG(((SR)), 6, kt);   /* my=g-1, dy=2 */ \
            if (t_ >= 1 && t_ <= 32)  MG(((RM)), 3, kt);   /* my=g,   dy=1 */ \
            if (t_ <= 31)             MG(((SN)), 0, kt);   /* my=g+1, dy=0 */ \
        }                                                                     \
    }                                                                         \
    if (t_ >= 2 && t_ <= 33) RETIRE(SR, t_ - 2);                              \
    if (t_ <= 31) {                                                           \
        *(uint4*)(ring + (SR) * ROWB + wu0) = Rv0;                            \
        *(uint4*)(ring + (SR) * ROWB + wu1) = Rv1;                            \
    }                                                                         \
    if (t_ < 33) __syncthreads();                                             \
} while (0)

// ---- pre-pass: feature f32 -> bf16 chunks; zero ws accumulators + flags ----
__global__ __launch_bounds__(256)
void nlwa_convert(const float* __restrict__ feature, uint4* __restrict__ fb,
                  float4* __restrict__ ws, int* __restrict__ flags)
{
    const int idx = blockIdx.x * 256 + threadIdx.x;   // 4*8*4096 = 131072
    if (idx < 16384) ws[idx] = make_float4(0.f, 0.f, 0.f, 0.f); // 256 pairs*64q
    if (blockIdx.x == 0) flags[threadIdx.x] = 0;      // 256 pair flags
    const int p = idx & (NPIX - 1);
    const int cb = idx >> 12;                         // b*8 + c  (0..31)
    const float* src = feature + (size_t)cb * 8 * NPIX + p;
    unsigned h[8];
#pragma unroll
    for (int j = 0; j < 8; ++j) {
        unsigned u = __float_as_uint(src[(size_t)j * NPIX]);
        u = u + 0x7fffu + ((u >> 16) & 1u);           // RNE to bf16
        h[j] = u >> 16;
    }
    fb[idx] = (uint4){h[0] | (h[1] << 16), h[2] | (h[3] << 16),
                      h[4] | (h[5] << 16), h[6] | (h[7] << 16)};
}

__global__ __launch_bounds__(256)
__attribute__((amdgpu_waves_per_eu(2)))
void nlwa_fused(const float* __restrict__ x_lab,
                const uint4* __restrict__ fb16,
                float4* __restrict__ ws,
                int* __restrict__ flags,
                float* __restrict__ out)
{
    __shared__ __align__(16) char ring[3 * ROWB];   // 25344 B
    __shared__ float xls[3 * XCH];                  // 24576 B
    __shared__ float part[3][4][64];                // 3072 B
    __shared__ float ssq[3][64];                    // 768 B
    __shared__ int amlast;

    const int tid = threadIdx.x;
    const int b = blockIdx.x >> 7;
    const int rem = blockIdx.x & 127;
    const int ny = rem >> 1, half = rem & 1;
    const int pr = blockIdx.x >> 1;                 // pair index (b,ny)
    const int R0 = half * 32;                       // first key row of half
    const int w = tid >> 6, lane = tid & 63;
    const int quad = lane >> 4, nl = lane & 15;
    const int kc0 = 2 * w, kc1 = 2 * w + 1;         // this thread's 2 kchunks
    const int x = lane;
    const int wu0 = (kc0 * 66 + x + 1) * 16;        // ds_write slots
    const int wu1 = (kc1 * 66 + x + 1) * 16;
    const int bu = (quad * 66 + nl) * 16;           // B fragment lane base

    const uint4* fbb = fb16 + (size_t)b * 8 * NPIX; // chunk (c,p) = fbb[c*NPIX+p]
    const float* xb = x_lab + (size_t)b * 3 * NPIX;

    // ---- stage x_lab[b] rows R0..R0+31 (24 KB) into LDS ----
    {
        const int base = R0 * 64;
        float4* d4 = (float4*)xls;
        for (int i = tid; i < 3 * XCH / 4; i += 256) {
            const int ch = i >> 9, off = i & 511;   // 512 float4 per channel
            d4[i] = *(const float4*)(xb + (size_t)ch * NPIX + base + off * 4);
        }
    }
    // ---- zero the pad units of all 3 ring slots ----
    if (tid < 48) {
        const int sl = tid / 16, pu = tid % 16;
        const int u = (pu >> 1) * 66 + (pu & 1) * 65;
        *(uint4*)(ring + sl * ROWB + u * 16) = (uint4){0u, 0u, 0u, 0u};
    }

    // ---- ssq partials for the 3 query rows (from bf16, rounds negM only) ----
#pragma unroll
    for (int dyi = 0; dyi < 3; ++dyi) {
        const int qr = ny + dyi - 1;
        float ss = 0.f;
        if (qr >= 0 && qr < 64) {
            const uint4 v0 = fbb[kc0 * NPIX + qr * 64 + x];
            const uint4 v1 = fbb[kc1 * NPIX + qr * 64 + x];
            const unsigned* pv0 = (const unsigned*)&v0;
            const unsigned* pv1 = (const unsigned*)&v1;
#pragma unroll
            for (int d = 0; d < 4; ++d) {
                float a0 = blo(pv0[d]), a1 = bhi(pv0[d]);
                float b0 = blo(pv1[d]), b1 = bhi(pv1[d]);
                ss = fmaf(a0, a0, ss); ss = fmaf(a1, a1, ss);
                ss = fmaf(b0, b0, ss); ss = fmaf(b1, b1, ss);
            }
        }
        part[dyi][w][x] = ss;
    }

    // ---- A fragments straight from global bf16 (L2-hot), predicated ----
    bf16x8 AF[18];
#pragma unroll
    for (int dyi = 0; dyi < 3; ++dyi) {
        const int qr = ny + dyi - 1;
#pragma unroll
        for (int dx = 0; dx < 3; ++dx) {
            const int cxx = w * 16 + nl + dx - 1;
#pragma unroll
            for (int ks = 0; ks < 2; ++ks) {
                bf16x8 t = (bf16x8){0, 0, 0, 0, 0, 0, 0, 0};
                if (qr >= 0 && qr < 64 && cxx >= 0 && cxx < 64)
                    t = *(const bf16x8*)(fbb + (quad + 4 * ks) * NPIX + qr * 64 + cxx);
                AF[(dyi * 3 + dx) * 2 + ks] = t;
            }
        }
    }

    // ---- stage key rows g(0)=R0-1 -> slot 0, g(1)=R0 -> slot 1 ----
#pragma unroll
    for (int rr = 0; rr < 2; ++rr) {
        const int g = R0 - 1 + rr;
        uint4 v0 = (uint4){0u, 0u, 0u, 0u}, v1 = v0;
        if (g >= 0) {
            v0 = fbb[kc0 * NPIX + g * 64 + x];
            v1 = fbb[kc1 * NPIX + g * 64 + x];
        }
        *(uint4*)(ring + rr * ROWB + wu0) = v0;
        *(uint4*)(ring + rr * ROWB + wu1) = v1;
    }
    __syncthreads();            // part + ring writes visible

    if (tid < 192) {
        const int dyi = tid >> 6, xx = tid & 63;
        float s = 0.f;
#pragma unroll
        for (int k = 0; k < 4; ++k) s += part[dyi][k][xx];
        ssq[dyi][xx] = s;
    }
    __syncthreads();            // ssq ready

    // ---- fixed softmax offsets (query side only; identical across halves) ----
    float negM[4];
#pragma unroll
    for (int rg = 0; rg < 4; ++rg) {
        const int q = w * 16 + quad * 4 + rg;
        float a = 0.f;
#pragma unroll
        for (int dyi = 0; dyi < 3; ++dyi)
#pragma unroll
            for (int dx = -1; dx <= 1; ++dx) {
                const int cx = q + dx;
                a += (cx >= 0 && cx < 64) ? ssq[dyi][cx] : 0.f;
            }
        negM[rg] = -SCALE * a;
    }

    float l_[4], A0[4], A1[4], A2[4];
#pragma unroll
    for (int rg = 0; rg < 4; ++rg) { l_[rg] = 0.f; A0[rg] = 0.f; A1[rg] = 0.f; A2[rg] = 0.f; }
    f32x4 acc[3][4];
#pragma unroll
    for (int i = 0; i < 3; ++i)
#pragma unroll
        for (int kt = 0; kt < 4; ++kt)
            acc[i][kt] = (f32x4){0.f, 0.f, 0.f, 0.f};

    // ---- 34 active steps (t=0..33; t=34,35 are guard-false no-ops) ----
    for (int rb = 0; rb < 36; rb += 3) {
        STEP(0, 1, 2, rb);
        STEP(1, 2, 0, rb + 1);
        STEP(2, 0, 1, rb + 2);
    }

    // ---- combine: shfl-reduce the 16 key cols within each quad group ----
#pragma unroll
    for (int rg = 0; rg < 4; ++rg) {
#pragma unroll
        for (int off = 8; off >= 1; off >>= 1) {
            l_[rg] += __shfl_down(l_[rg], off, 16);
            A0[rg] += __shfl_down(A0[rg], off, 16);
            A1[rg] += __shfl_down(A1[rg], off, 16);
            A2[rg] += __shfl_down(A2[rg], off, 16);
        }
    }
    // ---- partials -> pair-shared ws via device-scope atomics (no fence) ----
    if (nl == 0) {
#pragma unroll
        for (int rg = 0; rg < 4; ++rg) {
            const int q = w * 16 + quad * 4 + rg;
            float* p = (float*)(ws + (size_t)pr * 64 + q);
            atomicAdd(p + 0, l_[rg]);
            atomicAdd(p + 1, A0[rg]);
            atomicAdd(p + 2, A1[rg]);
            atomicAdd(p + 3, A2[rg]);
        }
    }
    // order: partial atomics complete (acked at coherent point) before flag
    asm volatile("s_waitcnt vmcnt(0)" ::: "memory");
    if (tid == 0)
        amlast = (atomicAdd(&flags[pr], 1) == 1);
    __syncthreads();
    if (amlast && tid < 64) {
        // coherent read-back of the summed partials (atomic 0-add)
        float* p = (float*)(ws + (size_t)pr * 64 + tid);
        const float lsum = atomicAdd(p + 0, 0.f);
        const float a0   = atomicAdd(p + 1, 0.f);
        const float a1   = atomicAdd(p + 2, 0.f);
        const float a2   = atomicAdd(p + 3, 0.f);
        const float inv = 1.0f / lsum;
        float* o = out + (size_t)b * 3 * NPIX + ny * 64 + tid;
        o[0]        = a0 * inv;
        o[NPIX]     = a1 * inv;
        o[2 * NPIX] = a2 * inv;
    }
}

extern "C" void kernel_launch(void* const* d_in, const int* in_sizes, int n_in,
                              void* d_out, int out_size, void* d_ws, size_t ws_size,
                              hipStream_t stream) {
    (void)in_sizes; (void)n_in; (void)out_size; (void)ws_size;
    const float* x_lab   = (const float*)d_in[0];
    const float* feature = (const float*)d_in[1];
    float* out = (float*)d_out;
    float4* wsp = (float4*)d_ws;                     // pair sums: 256*64*16 B = 256 KB
    uint4* fb   = (uint4*)((char*)d_ws + (1 << 20)); // bf16 feature: 2 MB
    int* flags  = (int*)((char*)d_ws + 3 * (1 << 20)); // 256 pair flags: 1 KB
    nlwa_convert<<<dim3(512), dim3(256), 0, stream>>>(feature, fb, wsp, flags);
    nlwa_fused<<<dim3(512), dim3(256), 0, stream>>>(x_lab, fb, wsp, flags, out);
}

// Round 18
// 126.458 us; speedup vs baseline: 1.0102x; 1.0102x over previous
//
#include <hip/hip_runtime.h>

// NonlocalWeightedAverage v21 == v14 restored (session-best verified:
// 125.7 us total / 79.4 us fused / absmax 0.0).
// Final session map -- every lever measured, all closed:
//   occupancy: 64-reg HW granule -> 2 waves/SIMD wall (v5-v10, 5 points);
//   >1-step barrier windows: >128 arch regs -> spill (v11/v13, + v9 forced);
//   LDS-read cuts: DPP dx-synthesis serializes MFMA operand chain (v15),
//     xls float4 interleave regresses (v19);
//   setprio: negative in 34-barrier lockstep regime (v16/v17 A/B);
//   combine folds: per-block async threadfence = L2 invalidation storm
//     (v16/v17); cooperative launch doesn't execute under graph capture
//     (v18); fenceless device-atomic fold correct but net-neutral (v20);
//   totals pinned ~126 +/- 2 by ~35-46 us fixed harness overhead.
// Structure: 512 blocks (4 batches x 64 query rows x 2 key halves), 4 waves;
// bf16 pre-convert kernel; 3-slot LDS ring streaming key rows with dy-reuse
// (each feature row's MFMA feeds targets my=g-1,g,g+1); fixed-max softmax
// via negM; per-step in-step staging (8-reg transient); combine kernel.

#define NPIX 4096
#define ROWB  (528 * 16)       // 8 kchunks * 66 xslots * 16 B = 8448 B
#define SCALE 10.0f
#define XCH   2048             // x floats per channel per block (32 rows * 64)

typedef __attribute__((ext_vector_type(8))) short bf16x8;
typedef __attribute__((ext_vector_type(4))) float f32x4;

#define MF(a, b, c) __builtin_amdgcn_mfma_f32_16x16x32_bf16(a, b, c, 0, 0, 0)

__device__ __forceinline__ float blo(unsigned u) { return __uint_as_float(u << 16); }
__device__ __forceinline__ float bhi(unsigned u) { return __uint_as_float(u & 0xffff0000u); }

// 6 MFMAs into acc[T][KT]: dx outer, ks inner (v4-proven order).
#define MG(T, DBASE, KT) do {                                                 \
    _Pragma("unroll")                                                         \
    for (int dx = 0; dx < 3; ++dx)                                            \
        _Pragma("unroll")                                                     \
        for (int ks = 0; ks < 2; ++ks)                                        \
            acc[T][KT] = MF(AF[((DBASE) + dx) * 2 + ks], B2[ks][dx], acc[T][KT]); \
} while (0)

// myv is LOCAL key row (0..31) within this block's half
#define RETIRE(S, myv) do {                                                   \
    _Pragma("unroll")                                                         \
    for (int kt = 0; kt < 4; ++kt) {                                          \
        const int kx = kt * 16 + nl;                                          \
        const float xv0 = xls[(myv) * 64 + kx];                               \
        const float xv1 = xls[XCH + (myv) * 64 + kx];                         \
        const float xv2 = xls[2 * XCH + (myv) * 64 + kx];                     \
        _Pragma("unroll")                                                     \
        for (int rg = 0; rg < 4; ++rg) {                                      \
            const float e = __expf(fmaf(acc[S][kt][rg], SCALE, negM[rg]));    \
            l_[rg] += e;                                                      \
            A0[rg] = fmaf(e, xv0, A0[rg]);                                    \
            A1[rg] = fmaf(e, xv1, A1[rg]);                                    \
            A2[rg] = fmaf(e, xv2, A2[rg]);                                    \
        }                                                                     \
        acc[S][kt] = (f32x4){0.f, 0.f, 0.f, 0.f};                             \
    }                                                                         \
} while (0)

// Step t: feature row g(t) = R0 - 1 + t, t = 0..33 (loop runs to 35, guards
// false at 34,35). Staging: issue 2 dwordx4 loads of row g(t+2) at step
// START (latency hides under the MFMAs); ds_write after retire; barrier.
#define STEP(RM, SN, SR, tt) do {                                             \
    const int t_ = (tt);                                                      \
    uint4 Rv0 = (uint4){0u, 0u, 0u, 0u}, Rv1 = (uint4){0u, 0u, 0u, 0u};       \
    if (t_ <= 31) {                                                           \
        const int g2 = R0 + 1 + t_;                                           \
        if (g2 < 64) {                                                        \
            Rv0 = fbb[kc0 * NPIX + g2 * 64 + x];                              \
            Rv1 = fbb[kc1 * NPIX + g2 * 64 + x];                              \
        }                                                                     \
    }                                                                         \
    if (t_ <= 33) {                                                           \
        const char* base = ring + (RM) * ROWB + bu;                           \
        _Pragma("unroll")                                                     \
        for (int kt = 0; kt < 4; ++kt) {                                      \
            bf16x8 B2[2][3];                                                  \
            _Pragma("unroll")                                                 \
            for (int ks = 0; ks < 2; ++ks) {                                  \
                const char* p = base + (ks * 264 + kt * 16) * 16;             \
                B2[ks][0] = *(const bf16x8*)(p);                              \
                B2[ks][1] = *(const bf16x8*)(p + 16);                         \
                B2[ks][2] = *(const bf16x8*)(p + 32);                         \
            }                                                                 \
            if (t_ >= 2)              MG(((SR)), 6, kt);   /* my=g-1, dy=2 */ \
            if (t_ >= 1 && t_ <= 32)  MG(((RM)), 3, kt);   /* my=g,   dy=1 */ \
            if (t_ <= 31)             MG(((SN)), 0, kt);   /* my=g+1, dy=0 */ \
        }                                                                     \
    }                                                                         \
    if (t_ >= 2 && t_ <= 33) RETIRE(SR, t_ - 2);                              \
    if (t_ <= 31) {                                                           \
        *(uint4*)(ring + (SR) * ROWB + wu0) = Rv0;                            \
        *(uint4*)(ring + (SR) * ROWB + wu1) = Rv1;                            \
    }                                                                         \
    if (t_ < 33) __syncthreads();                                             \
} while (0)

// ---- pre-pass: feature f32 -> bf16 chunks [b*8+c][p=4096][8 ch packed] ----
__global__ __launch_bounds__(256)
void nlwa_convert(const float* __restrict__ feature, uint4* __restrict__ fb)
{
    const int idx = blockIdx.x * 256 + threadIdx.x;   // 4*8*4096 = 131072
    const int p = idx & (NPIX - 1);
    const int cb = idx >> 12;                         // b*8 + c  (0..31)
    const float* src = feature + (size_t)cb * 8 * NPIX + p;
    unsigned h[8];
#pragma unroll
    for (int j = 0; j < 8; ++j) {
        unsigned u = __float_as_uint(src[(size_t)j * NPIX]);
        u = u + 0x7fffu + ((u >> 16) & 1u);           // RNE to bf16
        h[j] = u >> 16;
    }
    fb[idx] = (uint4){h[0] | (h[1] << 16), h[2] | (h[3] << 16),
                      h[4] | (h[5] << 16), h[6] | (h[7] << 16)};
}

__global__ __launch_bounds__(256)
__attribute__((amdgpu_waves_per_eu(2)))
void nlwa_fused(const float* __restrict__ x_lab,
                const uint4* __restrict__ fb16,
                float4* __restrict__ ws)
{
    __shared__ __align__(16) char ring[3 * ROWB];   // 25344 B
    __shared__ float xls[3 * XCH];                  // 24576 B
    __shared__ float part[3][4][64];                // 3072 B
    __shared__ float ssq[3][64];                    // 768 B
                                                    // total 53760 B -> 2 blk/CU

    const int tid = threadIdx.x;
    const int b = blockIdx.x >> 7;
    const int rem = blockIdx.x & 127;
    const int ny = rem >> 1, half = rem & 1;
    const int R0 = half * 32;                       // first key row of half
    const int w = tid >> 6, lane = tid & 63;
    const int quad = lane >> 4, nl = lane & 15;
    const int kc0 = 2 * w, kc1 = 2 * w + 1;         // this thread's 2 kchunks
    const int x = lane;
    const int wu0 = (kc0 * 66 + x + 1) * 16;        // ds_write slots
    const int wu1 = (kc1 * 66 + x + 1) * 16;
    const int bu = (quad * 66 + nl) * 16;           // B fragment lane base

    const uint4* fbb = fb16 + (size_t)b * 8 * NPIX; // chunk (c,p) = fbb[c*NPIX+p]
    const float* xb = x_lab + (size_t)b * 3 * NPIX;

    // ---- stage x_lab[b] rows R0..R0+31 (24 KB) into LDS ----
    {
        const int base = R0 * 64;
        float4* d4 = (float4*)xls;
        for (int i = tid; i < 3 * XCH / 4; i += 256) {
            const int ch = i >> 9, off = i & 511;   // 512 float4 per channel
            d4[i] = *(const float4*)(xb + (size_t)ch * NPIX + base + off * 4);
        }
    }
    // ---- zero the pad units of all 3 ring slots ----
    if (tid < 48) {
        const int sl = tid / 16, pu = tid % 16;
        const int u = (pu >> 1) * 66 + (pu & 1) * 65;
        *(uint4*)(ring + sl * ROWB + u * 16) = (uint4){0u, 0u, 0u, 0u};
    }

    // ---- ssq partials for the 3 query rows (from bf16, rounds negM only) ----
#pragma unroll
    for (int dyi = 0; dyi < 3; ++dyi) {
        const int qr = ny + dyi - 1;
        float ss = 0.f;
        if (qr >= 0 && qr < 64) {
            const uint4 v0 = fbb[kc0 * NPIX + qr * 64 + x];
            const uint4 v1 = fbb[kc1 * NPIX + qr * 64 + x];
            const unsigned* pv0 = (const unsigned*)&v0;
            const unsigned* pv1 = (const unsigned*)&v1;
#pragma unroll
            for (int d = 0; d < 4; ++d) {
                float a0 = blo(pv0[d]), a1 = bhi(pv0[d]);
                float b0 = blo(pv1[d]), b1 = bhi(pv1[d]);
                ss = fmaf(a0, a0, ss); ss = fmaf(a1, a1, ss);
                ss = fmaf(b0, b0, ss); ss = fmaf(b1, b1, ss);
            }
        }
        part[dyi][w][x] = ss;
    }

    // ---- A fragments straight from global bf16 (L2-hot), predicated ----
    bf16x8 AF[18];
#pragma unroll
    for (int dyi = 0; dyi < 3; ++dyi) {
        const int qr = ny + dyi - 1;
#pragma unroll
        for (int dx = 0; dx < 3; ++dx) {
            const int cxx = w * 16 + nl + dx - 1;
#pragma unroll
            for (int ks = 0; ks < 2; ++ks) {
                bf16x8 t = (bf16x8){0, 0, 0, 0, 0, 0, 0, 0};
                if (qr >= 0 && qr < 64 && cxx >= 0 && cxx < 64)
                    t = *(const bf16x8*)(fbb + (quad + 4 * ks) * NPIX + qr * 64 + cxx);
                AF[(dyi * 3 + dx) * 2 + ks] = t;
            }
        }
    }

    // ---- stage key rows g(0)=R0-1 -> slot 0, g(1)=R0 -> slot 1 ----
#pragma unroll
    for (int rr = 0; rr < 2; ++rr) {
        const int g = R0 - 1 + rr;
        uint4 v0 = (uint4){0u, 0u, 0u, 0u}, v1 = v0;
        if (g >= 0) {
            v0 = fbb[kc0 * NPIX + g * 64 + x];
            v1 = fbb[kc1 * NPIX + g * 64 + x];
        }
        *(uint4*)(ring + rr * ROWB + wu0) = v0;
        *(uint4*)(ring + rr * ROWB + wu1) = v1;
    }
    __syncthreads();            // part + ring writes visible

    if (tid < 192) {
        const int dyi = tid >> 6, xx = tid & 63;
        float s = 0.f;
#pragma unroll
        for (int k = 0; k < 4; ++k) s += part[dyi][k][xx];
        ssq[dyi][xx] = s;
    }
    __syncthreads();            // ssq ready

    // ---- fixed softmax offsets (query side only; identical across halves) ----
    float negM[4];
#pragma unroll
    for (int rg = 0; rg < 4; ++rg) {
        const int q = w * 16 + quad * 4 + rg;
        float a = 0.f;
#pragma unroll
        for (int dyi = 0; dyi < 3; ++dyi)
#pragma unroll
            for (int dx = -1; dx <= 1; ++dx) {
                const int cx = q + dx;
                a += (cx >= 0 && cx < 64) ? ssq[dyi][cx] : 0.f;
            }
        negM[rg] = -SCALE * a;
    }

    float l_[4], A0[4], A1[4], A2[4];
#pragma unroll
    for (int rg = 0; rg < 4; ++rg) { l_[rg] = 0.f; A0[rg] = 0.f; A1[rg] = 0.f; A2[rg] = 0.f; }
    f32x4 acc[3][4];
#pragma unroll
    for (int i = 0; i < 3; ++i)
#pragma unroll
        for (int kt = 0; kt < 4; ++kt)
            acc[i][kt] = (f32x4){0.f, 0.f, 0.f, 0.f};

    // ---- 34 active steps (t=0..33; t=34,35 are guard-false no-ops) ----
    for (int rb = 0; rb < 36; rb += 3) {
        STEP(0, 1, 2, rb);
        STEP(1, 2, 0, rb + 1);
        STEP(2, 0, 1, rb + 2);
    }

    // ---- combine: shfl-reduce the 16 key cols within each quad group ----
#pragma unroll
    for (int rg = 0; rg < 4; ++rg) {
#pragma unroll
        for (int off = 8; off >= 1; off >>= 1) {
            l_[rg] += __shfl_down(l_[rg], off, 16);
            A0[rg] += __shfl_down(A0[rg], off, 16);
            A1[rg] += __shfl_down(A1[rg], off, 16);
            A2[rg] += __shfl_down(A2[rg], off, 16);
        }
    }
    if (nl == 0) {
#pragma unroll
        for (int rg = 0; rg < 4; ++rg) {
            const int q = w * 16 + quad * 4 + rg;
            ws[(size_t)blockIdx.x * 64 + q] =
                make_float4(l_[rg], A0[rg], A1[rg], A2[rg]);
        }
    }
}

// Combine the two key-half partials and normalize. 4*64*64 = 16384 queries.
__global__ __launch_bounds__(256)
void nlwa_combine(const float4* __restrict__ ws, float* __restrict__ out)
{
    const int i = blockIdx.x * 256 + threadIdx.x;
    const int b = i >> 12, ny = (i >> 6) & 63, q = i & 63;
    const size_t base = ((size_t)(b * 64 + ny) * 2) * 64 + q;
    const float4 p0 = ws[base];
    const float4 p1 = ws[base + 64];
    const float inv = 1.0f / (p0.x + p1.x);
    float* o = out + (size_t)b * 3 * NPIX + ny * 64 + q;
    o[0]        = (p0.y + p1.y) * inv;
    o[NPIX]     = (p0.z + p1.z) * inv;
    o[2 * NPIX] = (p0.w + p1.w) * inv;
}

extern "C" void kernel_launch(void* const* d_in, const int* in_sizes, int n_in,
                              void* d_out, int out_size, void* d_ws, size_t ws_size,
                              hipStream_t stream) {
    (void)in_sizes; (void)n_in; (void)out_size; (void)ws_size;
    const float* x_lab   = (const float*)d_in[0];
    const float* feature = (const float*)d_in[1];
    float* out = (float*)d_out;
    float4* wsp = (float4*)d_ws;                     // partials: 512*64*16 B = 512 KB
    uint4* fb   = (uint4*)((char*)d_ws + (1 << 20)); // bf16 feature: 2 MB
    nlwa_convert<<<dim3(512), dim3(256), 0, stream>>>(feature, fb);
    nlwa_fused<<<dim3(512), dim3(256), 0, stream>>>(x_lab, fb, wsp);
    nlwa_combine<<<dim3(64), dim3(256), 0, stream>>>(wsp, out);
}